// Round 2
// baseline (168.455 us; speedup 1.0000x reference)
//
#include <hip/hip_runtime.h>

#define NUM_BINS 256
#define HW4 65536                  // 512*512/4 float4 per plane
#define PLANES 16                  // batch
#define BLOCKS_PER_GROUP 256
#define NGROUPS 6                  // {img1,img2} x {c0,c1,c2}
#define GRID (NGROUPS * BLOCKS_PER_GROUP)
#define THREADS 256

// ---------------------------------------------------------------------------
// Fused: per-(image,channel) LDS-private histograms -> global atomic flush ->
// last-block-out does normalize/cumsum/|cdf1-cdf2| and writes the scalar.
// ---------------------------------------------------------------------------
__global__ __launch_bounds__(THREADS) void hist_fused_kernel(
    const float* __restrict__ img1,
    const float* __restrict__ img2,
    unsigned int* __restrict__ hist /* [6][256] */,
    unsigned int* __restrict__ counter,
    float* __restrict__ out) {

    __shared__ unsigned int lh[4][NUM_BINS];   // one copy per wave
    __shared__ float red[THREADS / 64];
    __shared__ int isLast;

    const int t = threadIdx.x;
    lh[0][t] = 0u; lh[1][t] = 0u; lh[2][t] = 0u; lh[3][t] = 0u;
    __syncthreads();

    const int gid = blockIdx.x;
    const int group = gid >> 8;                 // 0..5
    const int blk = gid & (BLOCKS_PER_GROUP - 1);
    const int im = (group >= 3) ? 1 : 0;
    const int c = group - im * 3;
    // plane index == loop index (blk*256+t < 65536), so the address is
    // base + it * (3*HW4): one compile-time stride, no div/mod in the loop.
    const float4* __restrict__ src =
        (const float4*)(im ? img2 : img1) + (size_t)c * HW4 + blk * THREADS + t;
    unsigned int* lhw = lh[t >> 6];

    #pragma unroll 4
    for (int it = 0; it < PLANES; ++it) {
        const float4 v = src[(size_t)it * (3 * HW4)];
        const float xs[4] = {v.x, v.y, v.z, v.w};
        #pragma unroll
        for (int e = 0; e < 4; ++e) {
            const float x = xs[e];
            // torch.histc semantics: ignore outside [0,1]; x==1 -> last bin
            if (x >= 0.0f && x <= 1.0f) {
                int bi = (int)(x * 256.0f);          // trunc == floor (x>=0)
                bi = bi > (NUM_BINS - 1) ? (NUM_BINS - 1) : bi;
                atomicAdd(&lhw[bi], 1u);             // ds_add_u32 (no return)
            }
        }
    }
    __syncthreads();

    // flush: thread t owns bin t
    const unsigned int s = lh[0][t] + lh[1][t] + lh[2][t] + lh[3][t];
    if (s) atomicAdd(&hist[group * NUM_BINS + t], s);
    __syncthreads();                       // drains vmcnt before barrier

    // last-block gate (device-scope release/acquire)
    if (t == 0) {
        __threadfence();
        const unsigned int prev = atomicAdd(counter, 1u);
        isLast = (prev == (unsigned int)(GRID - 1));
    }
    __syncthreads();
    if (!isLast) return;
    __threadfence();

    // ---- finalize on the last block's 256 threads ----
    float* b1 = (float*)lh[0];             // reuse LDS
    float* b2 = (float*)lh[1];
    float acc = 0.0f;

    for (int ch = 0; ch < 3; ++ch) {
        // device-scope reads (atomic RMW +0) so no stale cache lines
        const float f1 = (float)atomicAdd(&hist[ch * NUM_BINS + t], 0u);
        const float f2 = (float)atomicAdd(&hist[(3 + ch) * NUM_BINS + t], 0u);
        b1[t] = f1;
        b2[t] = f2;
        __syncthreads();
        // Hillis-Steele inclusive scan, 8 steps
        for (int off = 1; off < NUM_BINS; off <<= 1) {
            float a1 = 0.0f, a2 = 0.0f;
            if (t >= off) { a1 = b1[t - off]; a2 = b2[t - off]; }
            __syncthreads();
            b1[t] += a1;
            b2[t] += a2;
            __syncthreads();
        }
        acc += fabsf(b1[t] / b1[NUM_BINS - 1] - b2[t] / b2[NUM_BINS - 1]);
        __syncthreads();                   // protect b1/b2 reuse next channel
    }

    #pragma unroll
    for (int off = 32; off > 0; off >>= 1)
        acc += __shfl_down(acc, off, 64);
    if ((t & 63) == 0) red[t >> 6] = acc;
    __syncthreads();
    if (t == 0)
        out[0] = (red[0] + red[1] + red[2] + red[3]) * (1.0f / 3.0f);
}

// ---------------------------------------------------------------------------
extern "C" void kernel_launch(void* const* d_in, const int* in_sizes, int n_in,
                              void* d_out, int out_size, void* d_ws,
                              size_t ws_size, hipStream_t stream) {
    const float* img1 = (const float*)d_in[0];
    const float* img2 = (const float*)d_in[1];
    float* out = (float*)d_out;
    unsigned int* hist = (unsigned int*)d_ws;            // [6][256] uint32
    unsigned int* counter = hist + NGROUPS * NUM_BINS;   // 1 uint32

    // d_ws is poisoned to 0xAA before every launch -> zero hist + counter
    hipMemsetAsync(d_ws, 0, (NGROUPS * NUM_BINS + 1) * sizeof(unsigned int),
                   stream);
    hist_fused_kernel<<<GRID, THREADS, 0, stream>>>(img1, img2, hist, counter,
                                                    out);
}